// Round 4
// baseline (490.965 us; speedup 1.0000x reference)
//
#include <hip/hip_runtime.h>

typedef unsigned short u16;
typedef __attribute__((ext_vector_type(8))) short short8;  // 8 bf16 (4 VGPRs) MFMA A/B frag
typedef __attribute__((ext_vector_type(4))) short short4v; // 4 bf16 (8B)
typedef __attribute__((ext_vector_type(4))) float f32x4;   // MFMA C/D frag

#define L_ROWS 200000
#define TM 64
#define LDP 136  // 128 + 8 bf16 pad

__device__ __forceinline__ float b2f(u16 u) {
  union { unsigned int i; float f; } v; v.i = ((unsigned int)u) << 16; return v.f;
}
__device__ __forceinline__ u16 f2b(float f) {  // RNE f32 -> bf16
  union { float fv; unsigned int i; } v; v.fv = f;
  return (u16)((v.i + 0x7fffu + ((v.i >> 16) & 1u)) >> 16);
}
// load 8 consecutive f32, round to bf16 frag
__device__ __forceinline__ short8 ldw8(const float* p) {
  short8 r;
#pragma unroll
  for (int j = 0; j < 8; j++) r[j] = (short)f2b(p[j]);
  return r;
}

// ---- kernel A: H = relu(X@Wh^T+bh); U0 = H@Wg0^T; U1 = H@Wg1^T (bf16, pitch-parametrized) ----
// U0/U1 may alias the X buffer (in-place interleaved, pitch=256): each block stages its own
// 64 X rows into LDS before any U store; footprints are block-disjoint.
__global__ __launch_bounds__(256) void kA(const float* X,
                                          const float* Wh,
                                          const float* bh,
                                          const float* Wg,
                                          u16* U0, u16* U1, int pitch) {
  __shared__ u16 tile[TM][LDP];  // X tile (bf16), then reused as H tile
  const int b = blockIdx.x, t = threadIdx.x;
  const int wave = t >> 6, lane = t & 63;
  const int ln = lane & 15, quad = lane >> 4;

  {  // stage X tile 64x128 f32 -> bf16 LDS; fully coalesced float4 loads
    const float* src = X + (size_t)b * TM * 128;
#pragma unroll
    for (int i = 0; i < 8; i++) {
      int e = t * 4 + i * 1024;             // flat element in 64x128 tile
      float4 v = *(const float4*)(src + e);
      u16 pk[4] = { f2b(v.x), f2b(v.y), f2b(v.z), f2b(v.w) };
      *(short4v*)&tile[e >> 7][e & 127] = *(short4v*)pk;
    }
  }

  // B frags, GEMM1 (H = X @ Wh^T): wave covers H cols [wave*32, wave*32+32)
  short8 bf1[2][4];
#pragma unroll
  for (int nt = 0; nt < 2; nt++) {
    int n = wave * 32 + nt * 16 + ln;
#pragma unroll
    for (int ks = 0; ks < 4; ks++) bf1[nt][ks] = ldw8(Wh + n * 128 + ks * 32 + quad * 8);
  }

  __syncthreads();

  f32x4 acc1[4][2] = {};
#pragma unroll
  for (int ks = 0; ks < 4; ks++) {
    short8 af[4];
#pragma unroll
    for (int mt = 0; mt < 4; mt++) af[mt] = *(const short8*)&tile[mt * 16 + ln][ks * 32 + quad * 8];
#pragma unroll
    for (int mt = 0; mt < 4; mt++)
#pragma unroll
      for (int nt = 0; nt < 2; nt++)
        acc1[mt][nt] = __builtin_amdgcn_mfma_f32_16x16x32_bf16(af[mt], bf1[nt][ks], acc1[mt][nt], 0, 0, 0);
  }

  __syncthreads();  // all X reads from LDS complete before H overwrite

  // H = relu(acc1 + bh) -> tile (bf16). D layout: col(n)=ln, row(m)=quad*4+reg  [m89/m91]
#pragma unroll
  for (int nt = 0; nt < 2; nt++) {
    int n = wave * 32 + nt * 16 + ln;
    float bias = bh[n];
#pragma unroll
    for (int r = 0; r < 4; r++)
#pragma unroll
      for (int mt = 0; mt < 4; mt++)
        tile[mt * 16 + quad * 4 + r][n] = f2b(fmaxf(acc1[mt][nt][r] + bias, 0.f));
  }

  __syncthreads();

  // GEMM2, N=256 fused: col n<128 -> U0 via Wg[n][0:128]; n>=128 -> U1 via Wg[n-128][128:256]
  short8 bf2[4][4];
#pragma unroll
  for (int nt = 0; nt < 4; nt++) {
    int n = wave * 64 + nt * 16 + ln;
    const float* base = (n < 128) ? (Wg + n * 256) : (Wg + (n - 128) * 256 + 128);
#pragma unroll
    for (int ks = 0; ks < 4; ks++) bf2[nt][ks] = ldw8(base + ks * 32 + quad * 8);
  }

  f32x4 acc2[4][4] = {};
#pragma unroll
  for (int ks = 0; ks < 4; ks++) {
    short8 af[4];
#pragma unroll
    for (int mt = 0; mt < 4; mt++) af[mt] = *(const short8*)&tile[mt * 16 + ln][ks * 32 + quad * 8];
#pragma unroll
    for (int mt = 0; mt < 4; mt++)
#pragma unroll
      for (int nt = 0; nt < 4; nt++)
        acc2[mt][nt] = __builtin_amdgcn_mfma_f32_16x16x32_bf16(af[mt], bf2[nt][ks], acc2[mt][nt], 0, 0, 0);
  }

#pragma unroll
  for (int nt = 0; nt < 4; nt++) {
    int n = wave * 64 + nt * 16 + ln;
    u16* dst = (n < 128) ? (U0 + n) : (U1 + (n - 128));
#pragma unroll
    for (int mt = 0; mt < 4; mt++)
#pragma unroll
      for (int r = 0; r < 4; r++) {
        size_t row = (size_t)(b * TM + mt * 16 + quad * 4 + r);
        dst[row * pitch] = f2b(acc2[mt][nt][r]);
      }
  }
}

// ---- kernel BC: acc = sum_s relu(U0[i0]+U1[i1]+bg); E = relu(acc/16);
//      E2 = relu(U0 + E@Wg1^T + bg); out = E2@Wf^T + bf (f32 out) ----
__global__ __launch_bounds__(256) void kBC(const int* __restrict__ perm,
                                           const u16* __restrict__ U0,
                                           const u16* __restrict__ U1,
                                           const float* __restrict__ Wg,
                                           const float* __restrict__ bg,
                                           const float* __restrict__ Wf,
                                           const float* __restrict__ bfs,
                                           float* __restrict__ out, int pitch) {
  __shared__ u16 Elds[TM][LDP];
  __shared__ float outacc[TM];
  const int b = blockIdx.x, t = threadIdx.x;
  const int wave = t >> 6, lane = t & 63;
  const int ln = lane & 15, quad = lane >> 4;

  if (t < TM) outacc[t] = 0.f;

  // phase 1: gather-accumulate. 4 threads/row, 32 f32 acc cols each.
  const int r = t >> 2, cq = (t & 3) * 32;
  const size_t i = (size_t)b * TM + r;
  float bgv[32];
#pragma unroll
  for (int k = 0; k < 32; k++) bgv[k] = bg[cq + k];

  float acc[32] = {};
  const int* pidx = perm + i * 32;  // perm[i][p][s] at i*32 + p*16 + s
#pragma unroll 2
  for (int s = 0; s < 16; s++) {
    int i0 = pidx[s];
    int i1 = pidx[16 + s];
    const u16* r0 = U0 + (size_t)i0 * pitch + cq;
    const u16* r1 = U1 + (size_t)i1 * pitch + cq;
    short8 a0[4], a1[4];
#pragma unroll
    for (int j = 0; j < 4; j++) { a0[j] = *(const short8*)(r0 + j * 8); a1[j] = *(const short8*)(r1 + j * 8); }
#pragma unroll
    for (int j = 0; j < 4; j++)
#pragma unroll
      for (int e = 0; e < 8; e++) {
        float v = b2f((u16)a0[j][e]) + b2f((u16)a1[j][e]) + bgv[j * 8 + e];
        acc[j * 8 + e] += fmaxf(v, 0.f);
      }
  }

  // E = relu(acc/16) -> LDS bf16
#pragma unroll
  for (int j = 0; j < 4; j++) {
    u16 pk[8];
#pragma unroll
    for (int e = 0; e < 8; e++) pk[e] = f2b(fmaxf(acc[j * 8 + e] * 0.0625f, 0.f));
    *(short8*)&Elds[r][cq + j * 8] = *(short8*)pk;
  }

  __syncthreads();

  // phase 2: D = E @ Wg1^T; wave covers n in [wave*32, wave*32+32)
  short8 bw[2][4];
#pragma unroll
  for (int nt = 0; nt < 2; nt++) {
    int n = wave * 32 + nt * 16 + ln;
#pragma unroll
    for (int ks = 0; ks < 4; ks++) bw[nt][ks] = ldw8(Wg + n * 256 + 128 + ks * 32 + quad * 8);
  }

  f32x4 d[4][2] = {};
#pragma unroll
  for (int ks = 0; ks < 4; ks++) {
    short8 af[4];
#pragma unroll
    for (int mt = 0; mt < 4; mt++) af[mt] = *(const short8*)&Elds[mt * 16 + ln][ks * 32 + quad * 8];
#pragma unroll
    for (int mt = 0; mt < 4; mt++)
#pragma unroll
      for (int nt = 0; nt < 2; nt++)
        d[mt][nt] = __builtin_amdgcn_mfma_f32_16x16x32_bf16(af[mt], bw[nt][ks], d[mt][nt], 0, 0, 0);
  }

  float wfv[2], bgv2[2];
  int ncol[2];
#pragma unroll
  for (int nt = 0; nt < 2; nt++) {
    ncol[nt] = wave * 32 + nt * 16 + ln;
    wfv[nt] = Wf[ncol[nt]];
    bgv2[nt] = bg[ncol[nt]];
  }

  // epilogue: E2 = relu(D + U0 + bg); dot with Wf; butterfly-reduce over the 16 ln-lanes
#pragma unroll
  for (int mt = 0; mt < 4; mt++)
#pragma unroll
    for (int rr = 0; rr < 4; rr++) {
      int row = mt * 16 + quad * 4 + rr;
      size_t grow = (size_t)b * TM + row;
      float p = 0.f;
#pragma unroll
      for (int nt = 0; nt < 2; nt++) {
        float u0v = b2f(U0[grow * pitch + ncol[nt]]);
        float e2 = fmaxf(d[mt][nt][rr] + u0v + bgv2[nt], 0.f);
        p += e2 * wfv[nt];
      }
      p += __shfl_xor(p, 1, 64);
      p += __shfl_xor(p, 2, 64);
      p += __shfl_xor(p, 4, 64);
      p += __shfl_xor(p, 8, 64);
      if (ln == 0) atomicAdd(&outacc[row], p);
    }

  __syncthreads();
  if (t < TM) out[(size_t)b * TM + t] = outacc[t] + bfs[0];
}

extern "C" void kernel_launch(void* const* d_in, const int* in_sizes, int n_in,
                              void* d_out, int out_size, void* d_ws, size_t ws_size,
                              hipStream_t stream) {
  const float* X  = (const float*)d_in[0];   // f32 per reference dtype
  const int* perm = (const int*)d_in[1];     // int32 per harness contract
  const float* Wh = (const float*)d_in[2];
  const float* bh = (const float*)d_in[3];
  const float* Wg = (const float*)d_in[4];
  const float* bg = (const float*)d_in[5];
  const float* Wf = (const float*)d_in[6];
  const float* bf = (const float*)d_in[7];
  float* out = (float*)d_out;

  const size_t uElems = (size_t)L_ROWS * 128;
  u16 *U0, *U1; int pitch;
  if (ws_size >= 2 * uElems * sizeof(u16)) {
    // preferred: both U matrices (bf16) in workspace, inputs untouched
    U0 = (u16*)d_ws; U1 = U0 + uElems; pitch = 128;
  } else {
    // fallback: interleave U0|U1 (bf16) into the X buffer footprint
    // (row i f32 = 512 B = 128 bf16 U0 + 128 bf16 U1; block-local WAR-safe;
    //  harness restores pristine X before every launch)
    U0 = (u16*)d_in[0]; U1 = U0 + 128; pitch = 256;
  }

  dim3 grid(L_ROWS / TM), block(256);
  kA<<<grid, block, 0, stream>>>(X, Wh, bh, Wg, U0, U1, pitch);
  kBC<<<grid, block, 0, stream>>>(perm, U0, U1, Wg, bg, Wf, bf, out, pitch);
}

// Round 5
// 409.814 us; speedup vs baseline: 1.1980x; 1.1980x over previous
//
#include <hip/hip_runtime.h>

typedef unsigned short u16;
typedef unsigned char u8;
typedef unsigned int u32;
typedef __attribute__((ext_vector_type(8))) short short8;  // 8 bf16 (4 VGPRs) MFMA A/B frag
typedef __attribute__((ext_vector_type(4))) short short4v; // 4 bf16 (8B)
typedef __attribute__((ext_vector_type(4))) float f32x4;   // MFMA C/D frag
typedef __attribute__((ext_vector_type(4))) u32 u32x4;

#define L_ROWS 200000
#define TM 64
#define LDP 136  // 128 + 8 bf16 pad

__device__ __forceinline__ float b2f(u16 u) {
  union { u32 i; float f; } v; v.i = ((u32)u) << 16; return v.f;
}
__device__ __forceinline__ u16 f2b(float f) {  // RNE f32 -> bf16
  union { float fv; u32 i; } v; v.fv = f;
  return (u16)((v.i + 0x7fffu + ((v.i >> 16) & 1u)) >> 16);
}
// load 8 consecutive f32 (two dwordx4), round to bf16 frag
__device__ __forceinline__ short8 ldw8(const float* p) {
  float4 a = *(const float4*)p;
  float4 b = *(const float4*)(p + 4);
  u16 pk[8] = { f2b(a.x), f2b(a.y), f2b(a.z), f2b(a.w),
                f2b(b.x), f2b(b.y), f2b(b.z), f2b(b.w) };
  return *(const short8*)pk;
}
// pack 4 f32 -> 4 e4m3 bytes in one u32 (HW RNE, OCP on gfx950)
__device__ __forceinline__ u32 pk4_fp8(float f0, float f1, float f2, float f3) {
  u32 w = __builtin_amdgcn_cvt_pk_fp8_f32(f0, f1, 0, false);
  w = __builtin_amdgcn_cvt_pk_fp8_f32(f2, f3, w, true);
  return w;
}

// ---- kernel A: H = relu(X@Wh^T+bh); U0 = H@Wg0^T; U1 = H@Wg1^T ----
// Outputs: bf16 U0 (epilogue) + fp8 U0/U1 (gather copies). May alias the X buffer
// (in-place: 512 B/row = bf16U0(256) | fp8U0(128) | fp8U1(128)); block-local WAR-safe
// since each block stages its 64 X rows into LDS before any store.
__global__ __launch_bounds__(256) void kA(const float* X,
                                          const float* Wh,
                                          const float* bh,
                                          const float* Wg,
                                          u16* U0b, int strideB,   // u16 elems/row
                                          u8* F0, u8* F1, int strideF) {  // bytes/row
  __shared__ u16 tile[TM][LDP];  // X tile -> H tile -> U staging
  const int b = blockIdx.x, t = threadIdx.x;
  const int wave = t >> 6, lane = t & 63;
  const int ln = lane & 15, quad = lane >> 4;

  {  // stage X tile 64x128 f32 -> bf16 LDS; coalesced float4 loads
    const float* src = X + (size_t)b * TM * 128;
#pragma unroll
    for (int i = 0; i < 8; i++) {
      int e = t * 4 + i * 1024;
      float4 v = *(const float4*)(src + e);
      u16 pk[4] = { f2b(v.x), f2b(v.y), f2b(v.z), f2b(v.w) };
      *(short4v*)&tile[e >> 7][e & 127] = *(const short4v*)pk;
    }
  }

  // B frags, GEMM1 (H = X @ Wh^T): wave covers H cols [wave*32, wave*32+32)
  short8 bf1[2][4];
#pragma unroll
  for (int nt = 0; nt < 2; nt++) {
    int n = wave * 32 + nt * 16 + ln;
#pragma unroll
    for (int ks = 0; ks < 4; ks++) bf1[nt][ks] = ldw8(Wh + n * 128 + ks * 32 + quad * 8);
  }

  __syncthreads();

  f32x4 acc1[4][2] = {};
#pragma unroll
  for (int ks = 0; ks < 4; ks++) {
    short8 af[4];
#pragma unroll
    for (int mt = 0; mt < 4; mt++) af[mt] = *(const short8*)&tile[mt * 16 + ln][ks * 32 + quad * 8];
#pragma unroll
    for (int mt = 0; mt < 4; mt++)
#pragma unroll
      for (int nt = 0; nt < 2; nt++)
        acc1[mt][nt] = __builtin_amdgcn_mfma_f32_16x16x32_bf16(af[mt], bf1[nt][ks], acc1[mt][nt], 0, 0, 0);
  }

  __syncthreads();  // X reads complete before H overwrite

  // H = relu(acc1 + bh) -> tile. D layout: col(n)=ln, row(m)=quad*4+reg
#pragma unroll
  for (int nt = 0; nt < 2; nt++) {
    int n = wave * 32 + nt * 16 + ln;
    float bias = bh[n];
#pragma unroll
    for (int r = 0; r < 4; r++)
#pragma unroll
      for (int mt = 0; mt < 4; mt++)
        tile[mt * 16 + quad * 4 + r][n] = f2b(fmaxf(acc1[mt][nt][r] + bias, 0.f));
  }

  __syncthreads();

  // GEMM2, N=256: wave w owns cols n = w*64 + nt*16 + ln (waves 0-1 -> U0, 2-3 -> U1)
  short8 bf2[4][4];
#pragma unroll
  for (int nt = 0; nt < 4; nt++) {
    int n = wave * 64 + nt * 16 + ln;
    const float* base = (n < 128) ? (Wg + n * 256) : (Wg + (n - 128) * 256 + 128);
#pragma unroll
    for (int ks = 0; ks < 4; ks++) bf2[nt][ks] = ldw8(base + ks * 32 + quad * 8);
  }

  f32x4 acc2[4][4] = {};
#pragma unroll
  for (int ks = 0; ks < 4; ks++) {
    short8 af[4];
#pragma unroll
    for (int mt = 0; mt < 4; mt++) af[mt] = *(const short8*)&tile[mt * 16 + ln][ks * 32 + quad * 8];
#pragma unroll
    for (int mt = 0; mt < 4; mt++)
#pragma unroll
      for (int nt = 0; nt < 4; nt++)
        acc2[mt][nt] = __builtin_amdgcn_mfma_f32_16x16x32_bf16(af[mt], bf2[nt][ks], acc2[mt][nt], 0, 0, 0);
  }

  __syncthreads();  // H reads complete before tile reuse

  // ---- pass 1: stage U0 (n<128) in LDS, then coalesced bf16 + fp8 stores ----
  if (wave < 2) {
#pragma unroll
    for (int nt = 0; nt < 4; nt++) {
      int n = wave * 64 + nt * 16 + ln;
#pragma unroll
      for (int mt = 0; mt < 4; mt++)
#pragma unroll
        for (int r = 0; r < 4; r++)
          tile[mt * 16 + quad * 4 + r][n] = f2b(acc2[mt][nt][r]);
    }
  }
  __syncthreads();
  {
    const int rr = t >> 2, cs = (t & 3) * 32;
    const size_t row = (size_t)b * TM + rr;
    u16* dstB = U0b + row * strideB + cs;
    u8* dstF = F0 + row * strideF + cs;
    u32 wpk[8];
#pragma unroll
    for (int c = 0; c < 4; c++) {
      short8 v = *(const short8*)&tile[rr][cs + c * 8];
      *(short8*)(dstB + c * 8) = v;
      wpk[c * 2 + 0] = pk4_fp8(b2f((u16)v[0]), b2f((u16)v[1]), b2f((u16)v[2]), b2f((u16)v[3]));
      wpk[c * 2 + 1] = pk4_fp8(b2f((u16)v[4]), b2f((u16)v[5]), b2f((u16)v[6]), b2f((u16)v[7]));
    }
    *(u32x4*)dstF = u32x4{wpk[0], wpk[1], wpk[2], wpk[3]};
    *(u32x4*)(dstF + 16) = u32x4{wpk[4], wpk[5], wpk[6], wpk[7]};
  }
  __syncthreads();

  // ---- pass 2: stage U1 (n>=128), fp8 store only ----
  if (wave >= 2) {
#pragma unroll
    for (int nt = 0; nt < 4; nt++) {
      int n = wave * 64 + nt * 16 + ln - 128;
#pragma unroll
      for (int mt = 0; mt < 4; mt++)
#pragma unroll
        for (int r = 0; r < 4; r++)
          tile[mt * 16 + quad * 4 + r][n] = f2b(acc2[mt][nt][r]);
    }
  }
  __syncthreads();
  {
    const int rr = t >> 2, cs = (t & 3) * 32;
    const size_t row = (size_t)b * TM + rr;
    u8* dstF = F1 + row * strideF + cs;
    u32 wpk[8];
#pragma unroll
    for (int c = 0; c < 4; c++) {
      short8 v = *(const short8*)&tile[rr][cs + c * 8];
      wpk[c * 2 + 0] = pk4_fp8(b2f((u16)v[0]), b2f((u16)v[1]), b2f((u16)v[2]), b2f((u16)v[3]));
      wpk[c * 2 + 1] = pk4_fp8(b2f((u16)v[4]), b2f((u16)v[5]), b2f((u16)v[6]), b2f((u16)v[7]));
    }
    *(u32x4*)dstF = u32x4{wpk[0], wpk[1], wpk[2], wpk[3]};
    *(u32x4*)(dstF + 16) = u32x4{wpk[4], wpk[5], wpk[6], wpk[7]};
  }
}

// ---- kernel BC: acc = sum_s relu(U0[i0]+U1[i1]+bg) [fp8 gathers]; E = relu(acc/16);
//      E2 = relu(U0_bf16 + E@Wg1^T + bg); out = E2@Wf^T + bf (f32) ----
__global__ __launch_bounds__(256) void kBC(const int* __restrict__ perm,
                                           const u16* __restrict__ U0b, int strideB,
                                           const u8* __restrict__ F0,
                                           const u8* __restrict__ F1, int strideF,
                                           const float* __restrict__ Wg,
                                           const float* __restrict__ bg,
                                           const float* __restrict__ Wf,
                                           const float* __restrict__ bfs,
                                           float* __restrict__ out) {
  __shared__ u16 Elds[TM][LDP];
  __shared__ float outacc[TM];
  const int b = blockIdx.x, t = threadIdx.x;
  const int wave = t >> 6, lane = t & 63;
  const int ln = lane & 15, quad = lane >> 4;

  if (t < TM) outacc[t] = 0.f;

  // phase 1: fp8 gather-accumulate. 4 threads/row, 32 cols (32 B) each.
  const int r = t >> 2, cq = (t & 3) * 32;
  const size_t i = (size_t)b * TM + r;
  float bgv[32];
#pragma unroll
  for (int k = 0; k < 32; k++) bgv[k] = bg[cq + k];

  float acc[32] = {};
  const int* pidx = perm + i * 32;  // perm[i][p][s] at i*32 + p*16 + s
#pragma unroll 2
  for (int s = 0; s < 16; s++) {
    int i0 = pidx[s];
    int i1 = pidx[16 + s];
    const u32x4* p0 = (const u32x4*)(F0 + (size_t)i0 * strideF + cq);
    const u32x4* p1 = (const u32x4*)(F1 + (size_t)i1 * strideF + cq);
    u32x4 a0 = p0[0], a1 = p0[1];
    u32x4 c0 = p1[0], c1 = p1[1];
#pragma unroll
    for (int k = 0; k < 4; k++) {
      u32 wa = a0[k], wb = c0[k];
      int e = k * 4;
      acc[e + 0] += fmaxf(__builtin_amdgcn_cvt_f32_fp8(wa, 0) + __builtin_amdgcn_cvt_f32_fp8(wb, 0) + bgv[e + 0], 0.f);
      acc[e + 1] += fmaxf(__builtin_amdgcn_cvt_f32_fp8(wa, 1) + __builtin_amdgcn_cvt_f32_fp8(wb, 1) + bgv[e + 1], 0.f);
      acc[e + 2] += fmaxf(__builtin_amdgcn_cvt_f32_fp8(wa, 2) + __builtin_amdgcn_cvt_f32_fp8(wb, 2) + bgv[e + 2], 0.f);
      acc[e + 3] += fmaxf(__builtin_amdgcn_cvt_f32_fp8(wa, 3) + __builtin_amdgcn_cvt_f32_fp8(wb, 3) + bgv[e + 3], 0.f);
    }
#pragma unroll
    for (int k = 0; k < 4; k++) {
      u32 wa = a1[k], wb = c1[k];
      int e = 16 + k * 4;
      acc[e + 0] += fmaxf(__builtin_amdgcn_cvt_f32_fp8(wa, 0) + __builtin_amdgcn_cvt_f32_fp8(wb, 0) + bgv[e + 0], 0.f);
      acc[e + 1] += fmaxf(__builtin_amdgcn_cvt_f32_fp8(wa, 1) + __builtin_amdgcn_cvt_f32_fp8(wb, 1) + bgv[e + 1], 0.f);
      acc[e + 2] += fmaxf(__builtin_amdgcn_cvt_f32_fp8(wa, 2) + __builtin_amdgcn_cvt_f32_fp8(wb, 2) + bgv[e + 2], 0.f);
      acc[e + 3] += fmaxf(__builtin_amdgcn_cvt_f32_fp8(wa, 3) + __builtin_amdgcn_cvt_f32_fp8(wb, 3) + bgv[e + 3], 0.f);
    }
  }

  // E = relu(acc/16) -> LDS bf16
#pragma unroll
  for (int j = 0; j < 4; j++) {
    u16 pk[8];
#pragma unroll
    for (int e = 0; e < 8; e++) pk[e] = f2b(fmaxf(acc[j * 8 + e] * 0.0625f, 0.f));
    *(short8*)&Elds[r][cq + j * 8] = *(const short8*)pk;
  }

  __syncthreads();

  // phase 2: D = E @ Wg1^T; wave covers n in [wave*32, wave*32+32)
  short8 bw[2][4];
#pragma unroll
  for (int nt = 0; nt < 2; nt++) {
    int n = wave * 32 + nt * 16 + ln;
#pragma unroll
    for (int ks = 0; ks < 4; ks++) bw[nt][ks] = ldw8(Wg + n * 256 + 128 + ks * 32 + quad * 8);
  }

  f32x4 d[4][2] = {};
#pragma unroll
  for (int ks = 0; ks < 4; ks++) {
    short8 af[4];
#pragma unroll
    for (int mt = 0; mt < 4; mt++) af[mt] = *(const short8*)&Elds[mt * 16 + ln][ks * 32 + quad * 8];
#pragma unroll
    for (int mt = 0; mt < 4; mt++)
#pragma unroll
      for (int nt = 0; nt < 2; nt++)
        d[mt][nt] = __builtin_amdgcn_mfma_f32_16x16x32_bf16(af[mt], bw[nt][ks], d[mt][nt], 0, 0, 0);
  }

  float wfv[2], bgv2[2];
  int ncol[2];
#pragma unroll
  for (int nt = 0; nt < 2; nt++) {
    ncol[nt] = wave * 32 + nt * 16 + ln;
    wfv[nt] = Wf[ncol[nt]];
    bgv2[nt] = bg[ncol[nt]];
  }

  // epilogue: E2 = relu(D + U0 + bg); dot with Wf; butterfly-reduce over 16 ln-lanes
#pragma unroll
  for (int mt = 0; mt < 4; mt++)
#pragma unroll
    for (int rr = 0; rr < 4; rr++) {
      int row = mt * 16 + quad * 4 + rr;
      size_t grow = (size_t)b * TM + row;
      float p = 0.f;
#pragma unroll
      for (int nt = 0; nt < 2; nt++) {
        float u0v = b2f(U0b[grow * strideB + ncol[nt]]);
        float e2 = fmaxf(d[mt][nt][rr] + u0v + bgv2[nt], 0.f);
        p += e2 * wfv[nt];
      }
      p += __shfl_xor(p, 1, 64);
      p += __shfl_xor(p, 2, 64);
      p += __shfl_xor(p, 4, 64);
      p += __shfl_xor(p, 8, 64);
      if (ln == 0) atomicAdd(&outacc[row], p);
    }

  __syncthreads();
  if (t < TM) out[(size_t)b * TM + t] = outacc[t] + bfs[0];
}

extern "C" void kernel_launch(void* const* d_in, const int* in_sizes, int n_in,
                              void* d_out, int out_size, void* d_ws, size_t ws_size,
                              hipStream_t stream) {
  const float* X  = (const float*)d_in[0];
  const int* perm = (const int*)d_in[1];
  const float* Wh = (const float*)d_in[2];
  const float* bh = (const float*)d_in[3];
  const float* Wg = (const float*)d_in[4];
  const float* bg = (const float*)d_in[5];
  const float* Wf = (const float*)d_in[6];
  const float* bf = (const float*)d_in[7];
  float* out = (float*)d_out;

  const size_t bfBytes = (size_t)L_ROWS * 128 * sizeof(u16);  // 51.2 MB
  const size_t f8Bytes = (size_t)L_ROWS * 128;                // 25.6 MB each

  u16* U0b; int strideB;
  u8 *F0, *F1; int strideF;
  if (ws_size >= bfBytes + 2 * f8Bytes) {
    // preferred: all in workspace, inputs untouched
    U0b = (u16*)d_ws;                    strideB = 128;
    F0 = (u8*)d_ws + bfBytes;            F1 = F0 + f8Bytes;   strideF = 128;
  } else {
    // fallback: in-place in X footprint. Row i (512 B): bf16U0 | fp8U0 | fp8U1.
    // Block-local WAR-safe; harness restores pristine X before every launch.
    u8* base = (u8*)d_in[0];
    U0b = (u16*)base;                    strideB = 256;
    F0 = base + 256;                     F1 = base + 384;     strideF = 512;
  }

  dim3 grid(L_ROWS / TM), block(256);
  kA<<<grid, block, 0, stream>>>(X, Wh, bh, Wg, U0b, strideB, F0, F1, strideF);
  kBC<<<grid, block, 0, stream>>>(perm, U0b, strideB, F0, F1, strideF, Wg, bg, Wf, bf, out);
}